// Round 1
// baseline (28389.941 us; speedup 1.0000x reference)
//
#include <hip/hip_runtime.h>
#include <math.h>

#define B_   128
#define L_   16
#define E_   768
#define D_   384
#define H_   12
#define HD_  64
#define NL_  6
#define SEQ_ 12
#define CH_  5                      // lidx per chunk (15 = 3 chunks)
#define MTOK (CH_*B_*SEQ_)          // 7680 tokens per chunk
#define LN_EPS 0.001f

// ---------------- XS = cos(X*omega + phase) ----------------
__global__ __launch_bounds__(256) void k_xs(const float* __restrict__ X,
                                            const float* __restrict__ om,
                                            const float* __restrict__ ph,
                                            float* __restrict__ XS) {
    int i = blockIdx.x * 256 + threadIdx.x;          // B*L*3*D = 2359296
    if (i >= B_*L_*3*D_) return;
    int d  = i % D_;
    int ch = (i / D_) % 3;
    int bt = i / (3*D_);
    XS[i] = cosf(X[bt*3 + ch] * om[ch*D_ + d] + ph[ch*D_ + d]);
}

// ---------------- build x0 for a chunk of 5 lidx ----------------
__global__ __launch_bounds__(256) void k_x0(const float* __restrict__ XS,
                                            const float* __restrict__ targets,
                                            const int* __restrict__ perms,
                                            float* __restrict__ x, int cb) {
    int i = blockIdx.x * 256 + threadIdx.x;          // MTOK*E
    if (i >= MTOK*E_) return;
    int e   = i % E_;
    int tok = i / E_;                                // (c*B + bi)*SEQ + s
    int s   = tok % SEQ_;
    int bi  = (tok / SEQ_) % B_;
    int c   = tok / (SEQ_*B_);
    int cl  = cb + c;                                // lidx-1
    int lidx = cl + 1;
    int pb  = perms[cl*B_ + bi];
    float val;
    if (s < 3) {
        int t = (e < D_) ? (L_ - lidx) : (L_ - lidx - 1);
        int d = (e < D_) ? e : (e - D_);
        val = XS[((pb*L_ + t)*3 + s)*D_ + d];
    } else if (s < 6) {
        int t = (17 - lidx) & 15;                    // (-lidx+1) mod 16
        val = targets[(pb*L_ + t)*3 + (s - 3)];
    } else {
        val = (float)(L_ - lidx);
    }
    x[i] = val;
}

// ---------------- LayerNorm (one token per block) ----------------
__global__ __launch_bounds__(256) void k_ln(const float* __restrict__ x,
                                            const float* __restrict__ g,
                                            const float* __restrict__ b,
                                            float* __restrict__ h) {
    __shared__ float red[256];
    int tok = blockIdx.x;
    int t = threadIdx.x;
    const float* xr = x + (size_t)tok * E_;
    float v0 = xr[t], v1 = xr[t+256], v2 = xr[t+512];
    red[t] = v0 + v1 + v2;
    __syncthreads();
    for (int o = 128; o > 0; o >>= 1) { if (t < o) red[t] += red[t+o]; __syncthreads(); }
    float mu = red[0] * (1.0f / E_);
    __syncthreads();
    float d0 = v0-mu, d1 = v1-mu, d2 = v2-mu;
    red[t] = d0*d0 + d1*d1 + d2*d2;
    __syncthreads();
    for (int o = 128; o > 0; o >>= 1) { if (t < o) red[t] += red[t+o]; __syncthreads(); }
    float rstd = rsqrtf(red[0] * (1.0f / E_) + LN_EPS);
    float* hr = h + (size_t)tok * E_;
    hr[t]     = d0 * rstd * g[t]     + b[t];
    hr[t+256] = d1 * rstd * g[t+256] + b[t+256];
    hr[t+512] = d2 * rstd * g[t+512] + b[t+512];
}

// ---------------- fp32 tiled GEMM: C (+)= A[MxK] @ W[KxN] (+bias)(relu) ----------------
#define BM 64
#define BN 64
#define BK 16
__global__ __launch_bounds__(256) void k_gemm(const float* __restrict__ A,
                                              const float* __restrict__ W,
                                              const float* __restrict__ bias,
                                              float* __restrict__ C,
                                              int M, int N, int K,
                                              int lda, int ldw, int ldc,
                                              int accum, int relu) {
    __shared__ __align__(16) float As[BK][BM + 4];   // ld 68: 16B-aligned rows, conflict-light
    __shared__ __align__(16) float Ws[BK][BN];
    int tid = threadIdx.x;
    int tx = tid & 15, ty = tid >> 4;
    int m0 = blockIdx.y * BM, n0 = blockIdx.x * BN;
    float acc[4][4] = {};
    int la_m = tid >> 2;             // 0..63
    int la_k = (tid & 3) * 4;        // 0,4,8,12
    int lw_k = tid >> 4;             // 0..15
    int lw_n = (tid & 15) * 4;       // 0..60
    for (int k0 = 0; k0 < K; k0 += BK) {
        float4 a4 = *(const float4*)&A[(size_t)(m0 + la_m) * lda + k0 + la_k];
        As[la_k+0][la_m] = a4.x; As[la_k+1][la_m] = a4.y;
        As[la_k+2][la_m] = a4.z; As[la_k+3][la_m] = a4.w;
        *(float4*)&Ws[lw_k][lw_n] = *(const float4*)&W[(size_t)(k0 + lw_k) * ldw + n0 + lw_n];
        __syncthreads();
        #pragma unroll
        for (int kk = 0; kk < BK; kk++) {
            float4 av = *(const float4*)&As[kk][ty*4];
            float4 wv = *(const float4*)&Ws[kk][tx*4];
            float a_[4] = {av.x, av.y, av.z, av.w};
            float w_[4] = {wv.x, wv.y, wv.z, wv.w};
            #pragma unroll
            for (int i = 0; i < 4; i++) {
                #pragma unroll
                for (int j = 0; j < 4; j++) acc[i][j] += a_[i] * w_[j];
            }
        }
        __syncthreads();
    }
    #pragma unroll
    for (int i = 0; i < 4; i++) {
        size_t off = (size_t)(m0 + ty*4 + i) * ldc + n0 + tx*4;
        float4 r;
        r.x = acc[i][0]; r.y = acc[i][1]; r.z = acc[i][2]; r.w = acc[i][3];
        if (bias) {
            r.x += bias[n0 + tx*4 + 0]; r.y += bias[n0 + tx*4 + 1];
            r.z += bias[n0 + tx*4 + 2]; r.w += bias[n0 + tx*4 + 3];
        }
        if (relu) {
            r.x = fmaxf(r.x, 0.f); r.y = fmaxf(r.y, 0.f);
            r.z = fmaxf(r.z, 0.f); r.w = fmaxf(r.w, 0.f);
        }
        if (accum) {
            float4 c4 = *(const float4*)&C[off];
            r.x += c4.x; r.y += c4.y; r.z += c4.z; r.w += c4.w;
        }
        *(float4*)&C[off] = r;
    }
}

// ---------------- attention: one (chunk-lidx, batch, head) per block ----------------
__global__ __launch_bounds__(256) void k_attn(const float* __restrict__ q,
                                              const float* __restrict__ k,
                                              const float* __restrict__ v,
                                              float* __restrict__ o) {
    __shared__ float qs[SEQ_][HD_], ks[SEQ_][HD_], vs[SEQ_][HD_];
    __shared__ float att[SEQ_][SEQ_];
    int blk = blockIdx.x;                 // (c*B + b)*H + h
    int hh  = blk % H_;
    int cbb = blk / H_;                   // c*B + b
    int t = threadIdx.x;
    size_t base = (size_t)cbb * SEQ_ * E_ + (size_t)hh * HD_;
    for (int i = t; i < SEQ_*HD_; i += 256) {
        int s = i / HD_, d = i % HD_;
        size_t g = base + (size_t)s * E_ + d;
        qs[s][d] = q[g]; ks[s][d] = k[g]; vs[s][d] = v[g];
    }
    __syncthreads();
    if (t < SEQ_*SEQ_) {
        int qi = t / SEQ_, kj = t % SEQ_;
        float s = 0.f;
        #pragma unroll
        for (int d = 0; d < HD_; d++) s += qs[qi][d] * ks[kj][d];
        att[qi][kj] = s * 0.125f;         // 1/sqrt(64)
    }
    __syncthreads();
    if (t < SEQ_) {
        float mx = -1e30f;
        #pragma unroll
        for (int j = 0; j < SEQ_; j++) mx = fmaxf(mx, att[t][j]);
        float e[SEQ_]; float sum = 0.f;
        #pragma unroll
        for (int j = 0; j < SEQ_; j++) { e[j] = expf(att[t][j] - mx); sum += e[j]; }
        float inv = 1.f / sum;
        #pragma unroll
        for (int j = 0; j < SEQ_; j++) att[t][j] = e[j] * inv;
    }
    __syncthreads();
    for (int i = t; i < SEQ_*HD_; i += 256) {
        int s = i / HD_, d = i % HD_;
        float acc = 0.f;
        #pragma unroll
        for (int j = 0; j < SEQ_; j++) acc += att[s][j] * vs[j][d];
        o[base + (size_t)s * E_ + d] = acc;
    }
}

// ---------------- logits: one (chunk-lidx, batch) row (9216) @ Wout(9216x3) ----------------
__global__ __launch_bounds__(256) void k_logits(const float* __restrict__ hfin,
                                                const float* __restrict__ Wout,
                                                const float* __restrict__ bout,
                                                float* __restrict__ logits, int cb) {
    __shared__ float red[3][256];
    int blk = blockIdx.x;                 // c*B + i
    int t = threadIdx.x;
    const float* row = hfin + (size_t)blk * SEQ_ * E_;
    float a0 = 0.f, a1 = 0.f, a2 = 0.f;
    for (int e = t; e < SEQ_*E_; e += 256) {
        float x = row[e];
        a0 += x * Wout[e*3 + 0]; a1 += x * Wout[e*3 + 1]; a2 += x * Wout[e*3 + 2];
    }
    red[0][t] = a0; red[1][t] = a1; red[2][t] = a2;
    __syncthreads();
    for (int o = 128; o > 0; o >>= 1) {
        if (t < o) { red[0][t] += red[0][t+o]; red[1][t] += red[1][t+o]; red[2][t] += red[2][t+o]; }
        __syncthreads();
    }
    if (t < 3) logits[((size_t)cb*B_ + blk)*3 + t] = red[t][0] + bout[t];
}

// ---------------- cost matrix for all 15 lidx ----------------
__global__ __launch_bounds__(256) void k_cost(const float* __restrict__ logits,
                                              const float* __restrict__ targets,
                                              float* __restrict__ cost) {
    int i = blockIdx.x * 256 + threadIdx.x;   // 15*128*128
    if (i >= 15*B_*B_) return;
    int j  = i & 127;
    int r  = (i >> 7) & 127;
    int cl = i >> 14;
    int lidx = cl + 1;
    const float* lg = &logits[(cl*B_ + r) * 3];
    const float* tg = &targets[((size_t)j*L_ + (L_ - lidx)) * 3];
    float d0 = lg[0]-tg[0], d1 = lg[1]-tg[1], d2 = lg[2]-tg[2];
    cost[i] = sqrtf(d0*d0 + d1*d1 + d2*d2 + 1e-12f);
}

// ---------------- greedy matching + per-lidx loss (one lidx per block) ----------------
__global__ __launch_bounds__(256) void k_match(const float* __restrict__ cost,
                                               const float* __restrict__ logits,
                                               const float* __restrict__ targets,
                                               float* __restrict__ losses) {
    __shared__ unsigned long long redk[256];
    __shared__ int rowTaken[B_], colTaken[B_], mrow[B_];
    __shared__ float lred[256];
    int cl = blockIdx.x, t = threadIdx.x;
    const float* cst = cost + (size_t)cl * B_ * B_;
    if (t < B_) { rowTaken[t] = 0; colTaken[t] = 0; }
    __syncthreads();
    for (int it = 0; it < B_; it++) {
        unsigned long long best = ~0ull;
        for (int e = t; e < B_*B_; e += 256) {
            int i = e >> 7, j = e & 127;
            if (rowTaken[i] | colTaken[j]) continue;
            unsigned long long key = ((unsigned long long)__float_as_uint(cst[e]) << 32)
                                     | (unsigned int)e;
            best = key < best ? key : best;
        }
        redk[t] = best;
        __syncthreads();
        for (int o = 128; o > 0; o >>= 1) {
            if (t < o) redk[t] = redk[t+o] < redk[t] ? redk[t+o] : redk[t];
            __syncthreads();
        }
        if (t == 0) {
            int e = (int)(redk[0] & 0xffffffffull);
            rowTaken[e >> 7] = 1; colTaken[e & 127] = 1; mrow[e >> 7] = e & 127;
        }
        __syncthreads();
    }
    int lidx = cl + 1;
    float a = 0.f;
    if (t < B_) {
        const float* lg = &logits[(cl*B_ + mrow[t]) * 3];   // lm[i] = logits[m[i]]
        const float* tg = &targets[((size_t)t*L_ + (L_ - lidx)) * 3];
        float d0 = lg[0]-tg[0], d1 = lg[1]-tg[1], d2 = lg[2]-tg[2];
        a = d0*d0 + d1*d1 + d2*d2;
    }
    lred[t] = a;
    __syncthreads();
    for (int o = 128; o > 0; o >>= 1) { if (t < o) lred[t] += lred[t+o]; __syncthreads(); }
    if (t == 0) losses[cl] = lred[0] * (1.0f / (B_*3));
}

__global__ void k_final(const float* __restrict__ losses, float* __restrict__ out) {
    float s = 0.f;
    for (int i = 0; i < 15; i++) s += losses[i];
    out[0] = s * (1.0f / 15.0f);
}

extern "C" void kernel_launch(void* const* d_in, const int* in_sizes, int n_in,
                              void* d_out, int out_size, void* d_ws, size_t ws_size,
                              hipStream_t stream) {
    (void)in_sizes; (void)n_in; (void)out_size; (void)ws_size;
    const float* X       = (const float*)d_in[0];
    const float* targets = (const float*)d_in[1];
    const float* omegas  = (const float*)d_in[2];
    const float* phases  = (const float*)d_in[3];
    const int*   perms   = (const int*)d_in[4];
    const float* Wq  = (const float*)d_in[5];
    const float* bq  = (const float*)d_in[6];
    const float* Wk  = (const float*)d_in[7];
    const float* bk  = (const float*)d_in[8];
    const float* Wv  = (const float*)d_in[9];
    const float* bv  = (const float*)d_in[10];
    const float* Wo  = (const float*)d_in[11];
    const float* bo  = (const float*)d_in[12];
    const float* ln1g = (const float*)d_in[13];
    const float* ln1b = (const float*)d_in[14];
    const float* ln2g = (const float*)d_in[15];
    const float* ln2b = (const float*)d_in[16];
    const float* W1  = (const float*)d_in[17];
    const float* b1f = (const float*)d_in[18];
    const float* W2  = (const float*)d_in[19];
    const float* b2f = (const float*)d_in[20];
    const float* lnfg = (const float*)d_in[21];
    const float* lnfb = (const float*)d_in[22];
    const float* Wout = (const float*)d_in[23];
    const float* bout = (const float*)d_in[24];

    float* ws = (float*)d_ws;
    const size_t SZ_XS  = (size_t)B_*L_*3*D_;      // 2,359,296
    const size_t SZ_ACT = (size_t)MTOK*E_;         // 5,898,240
    size_t o_XS = 0;
    size_t o_x  = o_XS + SZ_XS;
    size_t o_h  = o_x + SZ_ACT;
    size_t o_q  = o_h + SZ_ACT;
    size_t o_k  = o_q + SZ_ACT;
    size_t o_v  = o_k + SZ_ACT;
    size_t o_hid = o_q;                            // reuse q+k region (needs 7680*1536)
    size_t o_logits = o_v + SZ_ACT;
    size_t o_cost   = o_logits + 15*B_*3;
    size_t o_losses = o_cost + (size_t)15*B_*B_;
    // total ~32.1M floats = ~128.4 MB

    k_xs<<<(B_*L_*3*D_ + 255)/256, 256, 0, stream>>>(X, omegas, phases, ws + o_XS);

    dim3 g768(E_/BN, MTOK/BM);        // 12 x 120
    dim3 g1536(1536/BN, MTOK/BM);     // 24 x 120

    for (int cb = 0; cb < 15; cb += CH_) {
        k_x0<<<(MTOK*E_ + 255)/256, 256, 0, stream>>>(ws + o_XS, targets, perms, ws + o_x, cb);
        for (int l = 0; l < NL_; l++) {
            k_ln<<<MTOK, 256, 0, stream>>>(ws + o_x, ln1g + l*E_, ln1b + l*E_, ws + o_h);
            k_gemm<<<g768, 256, 0, stream>>>(ws + o_h, Wq + (size_t)l*E_*E_, bq + l*E_, ws + o_q,
                                             MTOK, E_, E_, E_, E_, E_, 0, 0);
            k_gemm<<<g768, 256, 0, stream>>>(ws + o_h, Wk + (size_t)l*E_*E_, bk + l*E_, ws + o_k,
                                             MTOK, E_, E_, E_, E_, E_, 0, 0);
            k_gemm<<<g768, 256, 0, stream>>>(ws + o_h, Wv + (size_t)l*E_*E_, bv + l*E_, ws + o_v,
                                             MTOK, E_, E_, E_, E_, E_, 0, 0);
            // attention writes o into the (now free) h buffer
            k_attn<<<CH_*B_*H_, 256, 0, stream>>>(ws + o_q, ws + o_k, ws + o_v, ws + o_h);
            // x += o @ Wo + bo
            k_gemm<<<g768, 256, 0, stream>>>(ws + o_h, Wo + (size_t)l*E_*E_, bo + l*E_, ws + o_x,
                                             MTOK, E_, E_, E_, E_, E_, 1, 0);
            k_ln<<<MTOK, 256, 0, stream>>>(ws + o_x, ln2g + l*E_, ln2b + l*E_, ws + o_h);
            for (int nc = 0; nc < 2; nc++) {
                // hidden = relu(h @ W1[:, nc*1536 : +1536] + b1f[...])
                k_gemm<<<g1536, 256, 0, stream>>>(ws + o_h,
                                                  W1 + (size_t)l*E_*3072 + nc*1536,
                                                  b1f + l*3072 + nc*1536,
                                                  ws + o_hid,
                                                  MTOK, 1536, E_, E_, 3072, 1536, 0, 1);
                // x += hidden @ W2[nc*1536 : +1536, :] (+ b2f once)
                k_gemm<<<g768, 256, 0, stream>>>(ws + o_hid,
                                                 W2 + ((size_t)l*3072 + nc*1536)*E_,
                                                 nc == 0 ? (b2f + l*E_) : (const float*)nullptr,
                                                 ws + o_x,
                                                 MTOK, E_, 1536, 1536, E_, E_, 1, 0);
            }
        }
        k_ln<<<MTOK, 256, 0, stream>>>(ws + o_x, lnfg, lnfb, ws + o_h);
        k_logits<<<CH_*B_, 256, 0, stream>>>(ws + o_h, Wout, bout, ws + o_logits, cb);
    }
    k_cost<<<(15*B_*B_ + 255)/256, 256, 0, stream>>>(ws + o_logits, targets, ws + o_cost);
    k_match<<<15, 256, 0, stream>>>(ws + o_cost, ws + o_logits, targets, ws + o_losses);
    k_final<<<1, 1, 0, stream>>>(ws + o_losses, (float*)d_out);
}

// Round 2
// 6315.407 us; speedup vs baseline: 4.4953x; 4.4953x over previous
//
#include <hip/hip_runtime.h>
#include <hip/hip_bf16.h>
#include <math.h>

#define B_   128
#define L_   16
#define E_   768
#define D_   384
#define H_   12
#define HD_  64
#define NL_  6
#define SEQ_ 12
#define CH_  5                      // lidx per chunk (15 = 3 chunks)
#define MTOK (CH_*B_*SEQ_)          // 7680 tokens per chunk
#define LN_EPS 0.001f

typedef __attribute__((ext_vector_type(8))) short bf16x8;   // 8 bf16 (4 VGPRs)
typedef __attribute__((ext_vector_type(4))) float f32x4;    // 4 fp32 acc

#define GLOAD_LDS16(g, l) \
    __builtin_amdgcn_global_load_lds((__attribute__((address_space(1))) const void*)(g), \
                                     (__attribute__((address_space(3))) void*)(l), 16, 0, 0)

// ---------------- XS = cos(X*omega + phase) ----------------
__global__ __launch_bounds__(256) void k_xs(const float* __restrict__ X,
                                            const float* __restrict__ om,
                                            const float* __restrict__ ph,
                                            float* __restrict__ XS) {
    int i = blockIdx.x * 256 + threadIdx.x;          // B*L*3*D = 2359296
    if (i >= B_*L_*3*D_) return;
    int d  = i % D_;
    int ch = (i / D_) % 3;
    int bt = i / (3*D_);
    XS[i] = cosf(X[bt*3 + ch] * om[ch*D_ + d] + ph[ch*D_ + d]);
}

// ---------------- build x0 for a chunk of 5 lidx ----------------
__global__ __launch_bounds__(256) void k_x0(const float* __restrict__ XS,
                                            const float* __restrict__ targets,
                                            const int* __restrict__ perms,
                                            float* __restrict__ x, int cb) {
    int i = blockIdx.x * 256 + threadIdx.x;          // MTOK*E
    if (i >= MTOK*E_) return;
    int e   = i % E_;
    int tok = i / E_;                                // (c*B + bi)*SEQ + s
    int s   = tok % SEQ_;
    int bi  = (tok / SEQ_) % B_;
    int c   = tok / (SEQ_*B_);
    int cl  = cb + c;                                // lidx-1
    int lidx = cl + 1;
    int pb  = perms[cl*B_ + bi];
    float val;
    if (s < 3) {
        int t = (e < D_) ? (L_ - lidx) : (L_ - lidx - 1);
        int d = (e < D_) ? e : (e - D_);
        val = XS[((pb*L_ + t)*3 + s)*D_ + d];
    } else if (s < 6) {
        int t = (17 - lidx) & 15;                    // (-lidx+1) mod 16
        val = targets[(pb*L_ + t)*3 + (s - 3)];
    } else {
        val = (float)(L_ - lidx);
    }
    x[i] = val;
}

// ---------------- LayerNorm fp32 in -> bf16 out ----------------
__global__ __launch_bounds__(256) void k_ln(const float* __restrict__ x,
                                            const float* __restrict__ g,
                                            const float* __restrict__ b,
                                            __hip_bfloat16* __restrict__ h) {
    __shared__ float red[256];
    int tok = blockIdx.x;
    int t = threadIdx.x;
    const float* xr = x + (size_t)tok * E_;
    float v0 = xr[t], v1 = xr[t+256], v2 = xr[t+512];
    red[t] = v0 + v1 + v2;
    __syncthreads();
    for (int o = 128; o > 0; o >>= 1) { if (t < o) red[t] += red[t+o]; __syncthreads(); }
    float mu = red[0] * (1.0f / E_);
    __syncthreads();
    float d0 = v0-mu, d1 = v1-mu, d2 = v2-mu;
    red[t] = d0*d0 + d1*d1 + d2*d2;
    __syncthreads();
    for (int o = 128; o > 0; o >>= 1) { if (t < o) red[t] += red[t+o]; __syncthreads(); }
    float rstd = rsqrtf(red[0] * (1.0f / E_) + LN_EPS);
    __hip_bfloat16* hr = h + (size_t)tok * E_;
    hr[t]     = __float2bfloat16(d0 * rstd * g[t]     + b[t]);
    hr[t+256] = __float2bfloat16(d1 * rstd * g[t+256] + b[t+256]);
    hr[t+512] = __float2bfloat16(d2 * rstd * g[t+512] + b[t+512]);
}

// ---------------- per-layer weight transpose+convert fp32[K][N] -> bf16[N][K] ----------------
// wl layout (bf16 elements): Wqkv_t[2304*768] @0 | Wo_t[768*768] @1769472 |
//                            W1_t[3072*768] @2359296 | W2_t[768*3072] @4718592
__global__ __launch_bounds__(256) void k_cvt(const float* __restrict__ Wq,
                                             const float* __restrict__ Wk,
                                             const float* __restrict__ Wv,
                                             const float* __restrict__ Wo,
                                             const float* __restrict__ W1,
                                             const float* __restrict__ W2,
                                             const float* __restrict__ bq,
                                             const float* __restrict__ bk,
                                             const float* __restrict__ bv,
                                             __hip_bfloat16* __restrict__ wl,
                                             float* __restrict__ bqkv, int l) {
    int bid = blockIdx.x;
    int tid = threadIdx.x;
    if (bid == 6912) {  // qkv bias combine
        for (int i = tid; i < 2304; i += 256) {
            float v = (i < 768) ? bq[l*768 + i] : (i < 1536) ? bk[l*768 + i - 768]
                                                             : bv[l*768 + i - 1536];
            bqkv[i] = v;
        }
        return;
    }
    const float* src; __hip_bfloat16* dst; int K, N, ti, tj;
    if (bid < 1728) {                      // Wq/Wk/Wv -> Wqkv_t rows [part*768, +768)
        int part = bid / 576, idx = bid % 576;
        const float* srcs[3] = {Wq, Wk, Wv};
        src = srcs[part] + (size_t)l*768*768; dst = wl + (size_t)part*768*768;
        K = 768; N = 768; tj = idx % 24; ti = idx / 24;
    } else if (bid < 2304) {               // Wo
        int idx = bid - 1728;
        src = Wo + (size_t)l*768*768; dst = wl + 1769472;
        K = 768; N = 768; tj = idx % 24; ti = idx / 24;
    } else if (bid < 4608) {               // W1 [768][3072] -> [3072][768]
        int idx = bid - 2304;
        src = W1 + (size_t)l*768*3072; dst = wl + 2359296;
        K = 768; N = 3072; tj = idx % 96; ti = idx / 96;
    } else {                               // W2 [3072][768] -> [768][3072]
        int idx = bid - 4608;
        src = W2 + (size_t)l*3072*768; dst = wl + 4718592;
        K = 3072; N = 768; tj = idx % 24; ti = idx / 24;
    }
    __shared__ float tbuf[32][33];
    int tx = tid & 31, ty = tid >> 5;      // 8 rows per pass
    #pragma unroll
    for (int p = 0; p < 4; p++) {
        int k = ti*32 + ty + p*8, n = tj*32 + tx;
        tbuf[ty + p*8][tx] = src[(size_t)k*N + n];
    }
    __syncthreads();
    #pragma unroll
    for (int p = 0; p < 4; p++) {
        int n = tj*32 + ty + p*8, k = ti*32 + tx;
        dst[(size_t)n*K + k] = __float2bfloat16(tbuf[tx][ty + p*8]);
    }
}

// ---------------- bf16 MFMA GEMM: C(+)= A[M][K] @ Bt[N][K]^T (+bias)(relu) ----------------
// 128x128 tile, BK=32, 4 waves (2x2 of 64x64), 16x16x32 MFMA, global_load_lds staging.
// LDS data placement swizzle: slot (row r, pos p) holds k-group p ^ ((r>>1)&3).
// flags: 1 = bf16 out, 2 = fp32 accumulate (+=), 4 = relu
__global__ __launch_bounds__(256) void k_gemm_bf16(const __hip_bfloat16* __restrict__ A,
                                                   const __hip_bfloat16* __restrict__ Bt,
                                                   const float* __restrict__ bias,
                                                   void* __restrict__ Cp,
                                                   int K, int ldc, int flags) {
    __shared__ __align__(16) char smem[16384];
    char* As = smem;            // 128 rows x 64 B
    char* Bs = smem + 8192;
    int tid = threadIdx.x;
    int lane = tid & 63;
    int w = tid >> 6;
    int wm = (w >> 1) * 64, wn = (w & 1) * 64;
    int m0 = blockIdx.y * 128, n0 = blockIdx.x * 128;

    // staging slots: u1 = tid, u2 = tid + 256 (16B units); row = u>>2, pos = u&3
    int u1 = tid, u2 = tid + 256;
    int r1 = u1 >> 2, kg1 = ((u1 & 3) ^ ((r1 >> 1) & 3)) * 8;
    int r2 = u2 >> 2, kg2 = ((u2 & 3) ^ ((r2 >> 1) & 3)) * 8;

    f32x4 acc[4][4] = {};
    int fr = lane & 15, fkg = lane >> 4;

    for (int k0 = 0; k0 < K; k0 += 32) {
        GLOAD_LDS16(A  + (size_t)(m0 + r1) * K + k0 + kg1, As + u1 * 16);
        GLOAD_LDS16(A  + (size_t)(m0 + r2) * K + k0 + kg2, As + u2 * 16);
        GLOAD_LDS16(Bt + (size_t)(n0 + r1) * K + k0 + kg1, Bs + u1 * 16);
        GLOAD_LDS16(Bt + (size_t)(n0 + r2) * K + k0 + kg2, Bs + u2 * 16);
        __syncthreads();
        bf16x8 a[4], b[4];
        #pragma unroll
        for (int i = 0; i < 4; i++) {
            int m = wm + i*16 + fr;
            a[i] = *(const bf16x8*)(As + m*64 + ((fkg ^ ((m >> 1) & 3)) * 16));
            int n = wn + i*16 + fr;
            b[i] = *(const bf16x8*)(Bs + n*64 + ((fkg ^ ((n >> 1) & 3)) * 16));
        }
        #pragma unroll
        for (int i = 0; i < 4; i++)
            #pragma unroll
            for (int j = 0; j < 4; j++)
                acc[i][j] = __builtin_amdgcn_mfma_f32_16x16x32_bf16(a[i], b[j], acc[i][j], 0, 0, 0);
        __syncthreads();
    }

    // C/D layout: col = lane&15, row = (lane>>4)*4 + reg
    int colL = lane & 15, rowg = (lane >> 4) * 4;
    #pragma unroll
    for (int i = 0; i < 4; i++) {
        #pragma unroll
        for (int j = 0; j < 4; j++) {
            int col = n0 + wn + j*16 + colL;
            float bv = bias ? bias[col] : 0.0f;
            #pragma unroll
            for (int r = 0; r < 4; r++) {
                int row = m0 + wm + i*16 + rowg + r;
                float v = acc[i][j][r] + bv;
                if (flags & 4) v = fmaxf(v, 0.0f);
                size_t off = (size_t)row * ldc + col;
                if (flags & 1)      ((__hip_bfloat16*)Cp)[off] = __float2bfloat16(v);
                else if (flags & 2) ((float*)Cp)[off] += v;
                else                ((float*)Cp)[off] = v;
            }
        }
    }
}

// ---------------- attention: qkv bf16 [tok][2304] -> o bf16 [tok][768] ----------------
__global__ __launch_bounds__(256) void k_attn(const __hip_bfloat16* __restrict__ qkv,
                                              __hip_bfloat16* __restrict__ o) {
    __shared__ float qs[SEQ_][HD_], ks[SEQ_][HD_], vs[SEQ_][HD_];
    __shared__ float att[SEQ_][SEQ_];
    int blk = blockIdx.x;                 // (c*B + b)*H + h
    int hh  = blk % H_;
    int cbb = blk / H_;
    int t = threadIdx.x;
    for (int i = t; i < SEQ_*HD_; i += 256) {
        int s = i / HD_, d = i % HD_;
        size_t g = (size_t)(cbb*SEQ_ + s) * 2304 + hh*64 + d;
        qs[s][d] = __bfloat162float(qkv[g]);
        ks[s][d] = __bfloat162float(qkv[g + 768]);
        vs[s][d] = __bfloat162float(qkv[g + 1536]);
    }
    __syncthreads();
    if (t < SEQ_*SEQ_) {
        int qi = t / SEQ_, kj = t % SEQ_;
        float s = 0.f;
        #pragma unroll
        for (int d = 0; d < HD_; d++) s += qs[qi][d] * ks[kj][d];
        att[qi][kj] = s * 0.125f;
    }
    __syncthreads();
    if (t < SEQ_) {
        float mx = -1e30f;
        #pragma unroll
        for (int j = 0; j < SEQ_; j++) mx = fmaxf(mx, att[t][j]);
        float e[SEQ_]; float sum = 0.f;
        #pragma unroll
        for (int j = 0; j < SEQ_; j++) { e[j] = expf(att[t][j] - mx); sum += e[j]; }
        float inv = 1.f / sum;
        #pragma unroll
        for (int j = 0; j < SEQ_; j++) att[t][j] = e[j] * inv;
    }
    __syncthreads();
    for (int i = t; i < SEQ_*HD_; i += 256) {
        int s = i / HD_, d = i % HD_;
        float acc = 0.f;
        #pragma unroll
        for (int j = 0; j < SEQ_; j++) acc += att[s][j] * vs[j][d];
        o[(size_t)(cbb*SEQ_ + s) * 768 + hh*64 + d] = __float2bfloat16(acc);
    }
}

// ---------------- logits: bf16 h row (9216) @ Wout(9216x3) ----------------
__global__ __launch_bounds__(256) void k_logits(const __hip_bfloat16* __restrict__ hfin,
                                                const float* __restrict__ Wout,
                                                const float* __restrict__ bout,
                                                float* __restrict__ logits, int cb) {
    __shared__ float red[3][256];
    int blk = blockIdx.x;
    int t = threadIdx.x;
    const __hip_bfloat16* row = hfin + (size_t)blk * SEQ_ * E_;
    float a0 = 0.f, a1 = 0.f, a2 = 0.f;
    for (int e = t; e < SEQ_*E_; e += 256) {
        float x = __bfloat162float(row[e]);
        a0 += x * Wout[e*3 + 0]; a1 += x * Wout[e*3 + 1]; a2 += x * Wout[e*3 + 2];
    }
    red[0][t] = a0; red[1][t] = a1; red[2][t] = a2;
    __syncthreads();
    for (int o = 128; o > 0; o >>= 1) {
        if (t < o) { red[0][t] += red[0][t+o]; red[1][t] += red[1][t+o]; red[2][t] += red[2][t+o]; }
        __syncthreads();
    }
    if (t < 3) logits[((size_t)cb*B_ + blk)*3 + t] = red[t][0] + bout[t];
}

// ---------------- cost matrix for all 15 lidx ----------------
__global__ __launch_bounds__(256) void k_cost(const float* __restrict__ logits,
                                              const float* __restrict__ targets,
                                              float* __restrict__ cost) {
    int i = blockIdx.x * 256 + threadIdx.x;   // 15*128*128
    if (i >= 15*B_*B_) return;
    int j  = i & 127;
    int r  = (i >> 7) & 127;
    int cl = i >> 14;
    int lidx = cl + 1;
    const float* lg = &logits[(cl*B_ + r) * 3];
    const float* tg = &targets[((size_t)j*L_ + (L_ - lidx)) * 3];
    float d0 = lg[0]-tg[0], d1 = lg[1]-tg[1], d2 = lg[2]-tg[2];
    cost[i] = sqrtf(d0*d0 + d1*d1 + d2*d2 + 1e-12f);
}

// ---------------- greedy matching: register-resident keys, branchless kill ----------------
__global__ __launch_bounds__(256) void k_match(const float* __restrict__ cost,
                                               const float* __restrict__ logits,
                                               const float* __restrict__ targets,
                                               float* __restrict__ losses) {
    __shared__ unsigned long long wred[4];
    __shared__ int mrow[B_];
    __shared__ unsigned int winner;
    __shared__ float lred[256];
    int cl = blockIdx.x, t = threadIdx.x;
    const float* cst = cost + (size_t)cl * B_ * B_;
    unsigned long long key[64];
    #pragma unroll
    for (int n = 0; n < 64; n++) {
        unsigned e = n * 256 + t;             // coalesced
        key[n] = ((unsigned long long)__float_as_uint(cst[e]) << 32) | e;
    }
    int lane = t & 63, w = t >> 6;
    for (int it = 0; it < B_; it++) {
        unsigned long long best = ~0ull;
        #pragma unroll
        for (int n = 0; n < 64; n++) best = key[n] < best ? key[n] : best;
        #pragma unroll
        for (int o = 32; o > 0; o >>= 1) {
            unsigned long long other = __shfl_down(best, o, 64);
            best = other < best ? other : best;
        }
        if (lane == 0) wred[w] = best;
        __syncthreads();
        if (t == 0) {
            unsigned long long b = wred[0];
            if (wred[1] < b) b = wred[1];
            if (wred[2] < b) b = wred[2];
            if (wred[3] < b) b = wred[3];
            unsigned e = (unsigned)b;
            winner = e;
            mrow[(e >> 7) & 127] = e & 127;
        }
        __syncthreads();
        unsigned e = winner;
        unsigned wi = (e >> 7) & 127, wj = e & 127;
        #pragma unroll
        for (int n = 0; n < 64; n++) {
            unsigned ke = (unsigned)key[n];
            if ((((ke >> 7) & 127) == wi) | ((ke & 127) == wj)) key[n] = ~0ull;
        }
        __syncthreads();
    }
    int lidx = cl + 1;
    float a = 0.f;
    if (t < B_) {
        const float* lg = &logits[(cl*B_ + mrow[t]) * 3];
        const float* tg = &targets[((size_t)t*L_ + (L_ - lidx)) * 3];
        float d0 = lg[0]-tg[0], d1 = lg[1]-tg[1], d2 = lg[2]-tg[2];
        a = d0*d0 + d1*d1 + d2*d2;
    }
    lred[t] = a;
    __syncthreads();
    for (int o = 128; o > 0; o >>= 1) { if (t < o) lred[t] += lred[t+o]; __syncthreads(); }
    if (t == 0) losses[cl] = lred[0] * (1.0f / (B_*3));
}

__global__ void k_final(const float* __restrict__ losses, float* __restrict__ out) {
    float s = 0.f;
    for (int i = 0; i < 15; i++) s += losses[i];
    out[0] = s * (1.0f / 15.0f);
}

extern "C" void kernel_launch(void* const* d_in, const int* in_sizes, int n_in,
                              void* d_out, int out_size, void* d_ws, size_t ws_size,
                              hipStream_t stream) {
    (void)in_sizes; (void)n_in; (void)out_size; (void)ws_size;
    const float* X       = (const float*)d_in[0];
    const float* targets = (const float*)d_in[1];
    const float* omegas  = (const float*)d_in[2];
    const float* phases  = (const float*)d_in[3];
    const int*   perms   = (const int*)d_in[4];
    const float* Wq  = (const float*)d_in[5];
    const float* bq  = (const float*)d_in[6];
    const float* Wk  = (const float*)d_in[7];
    const float* bk  = (const float*)d_in[8];
    const float* Wv  = (const float*)d_in[9];
    const float* bv  = (const float*)d_in[10];
    const float* Wo  = (const float*)d_in[11];
    const float* bo  = (const float*)d_in[12];
    const float* ln1g = (const float*)d_in[13];
    const float* ln1b = (const float*)d_in[14];
    const float* ln2g = (const float*)d_in[15];
    const float* ln2b = (const float*)d_in[16];
    const float* W1  = (const float*)d_in[17];
    const float* b1f = (const float*)d_in[18];
    const float* W2  = (const float*)d_in[19];
    const float* b2f = (const float*)d_in[20];
    const float* lnfg = (const float*)d_in[21];
    const float* lnfb = (const float*)d_in[22];
    const float* Wout = (const float*)d_in[23];
    const float* bout = (const float*)d_in[24];

    // ---- workspace layout (bytes), total ~102.2 MiB ----
    char* wsb = (char*)d_ws;
    float*          XS     = (float*)(wsb);                        //  9,437,184 B
    float*          x      = (float*)(wsb + 9437184);              // 23,592,960 B
    __hip_bfloat16* h      = (__hip_bfloat16*)(wsb + 33030144);    // 11,796,480 B
    __hip_bfloat16* qkvh   = (__hip_bfloat16*)(wsb + 44826624);    // 47,185,920 B (qkv | ffn hidden)
    __hip_bfloat16* wl     = (__hip_bfloat16*)(wsb + 92012544);    // 14,155,776 B per-layer weights
    float*          bqkv   = (float*)(wsb + 106168320);            //      9,216 B
    float*          logits = (float*)(wsb + 106177536);            //     23,040 B
    float*          costb  = (float*)(wsb + 106200576);            //    983,040 B
    float*          losses = (float*)(wsb + 107183616);            //         60 B

    k_xs<<<(B_*L_*3*D_ + 255)/256, 256, 0, stream>>>(X, omegas, phases, XS);

    dim3 gQKV(2304/128, MTOK/128);   // 18 x 60
    dim3 gO  (768/128,  MTOK/128);   //  6 x 60
    dim3 gF1 (3072/128, MTOK/128);   // 24 x 60
    dim3 gF2 (768/128,  MTOK/128);   //  6 x 60

    for (int cb = 0; cb < 15; cb += CH_) {
        k_x0<<<(MTOK*E_ + 255)/256, 256, 0, stream>>>(XS, targets, perms, x, cb);
        for (int l = 0; l < NL_; l++) {
            k_cvt<<<6913, 256, 0, stream>>>(Wq, Wk, Wv, Wo, W1, W2, bq, bk, bv, wl, bqkv, l);
            k_ln<<<MTOK, 256, 0, stream>>>(x, ln1g + l*E_, ln1b + l*E_, h);
            k_gemm_bf16<<<gQKV, 256, 0, stream>>>(h, wl, bqkv, qkvh, 768, 2304, 1);
            k_attn<<<CH_*B_*H_, 256, 0, stream>>>(qkvh, h);      // o -> h (bf16)
            k_gemm_bf16<<<gO, 256, 0, stream>>>(h, wl + 1769472, bo + l*E_, x, 768, 768, 2);
            k_ln<<<MTOK, 256, 0, stream>>>(x, ln2g + l*E_, ln2b + l*E_, h);
            k_gemm_bf16<<<gF1, 256, 0, stream>>>(h, wl + 2359296, b1f + l*3072, qkvh, 768, 3072, 1|4);
            k_gemm_bf16<<<gF2, 256, 0, stream>>>(qkvh, wl + 4718592, b2f + l*E_, x, 3072, 768, 2);
        }
        k_ln<<<MTOK, 256, 0, stream>>>(x, lnfg, lnfb, h);
        k_logits<<<CH_*B_, 256, 0, stream>>>(h, Wout, bout, logits, cb);
    }
    k_cost<<<(15*B_*B_ + 255)/256, 256, 0, stream>>>(logits, targets, costb);
    k_match<<<15, 256, 0, stream>>>(costb, logits, targets, losses);
    k_final<<<1, 1, 0, stream>>>(losses, (float*)d_out);
}

// Round 3
// 5516.470 us; speedup vs baseline: 5.1464x; 1.1448x over previous
//
#include <hip/hip_runtime.h>
#include <hip/hip_bf16.h>
#include <math.h>

#define B_   128
#define L_   16
#define E_   768
#define D_   384
#define H_   12
#define HD_  64
#define NL_  6
#define SEQ_ 12
#define CH_  5                      // lidx per chunk (15 = 3 chunks)
#define MTOK (CH_*B_*SEQ_)          // 7680 tokens per chunk
#define LN_EPS 0.001f
#define WLS   7077888               // bf16 elems per layer weight pack
#define BQS   2304

typedef __attribute__((ext_vector_type(8))) short bf16x8;
typedef __attribute__((ext_vector_type(4))) float f32x4;

#define GLOAD_LDS16(g, l) \
    __builtin_amdgcn_global_load_lds((__attribute__((address_space(1))) const void*)(g), \
                                     (__attribute__((address_space(3))) void*)(l), 16, 0, 0)

// ---------------- XS = cos(X*omega + phase) ----------------
__global__ __launch_bounds__(256) void k_xs(const float* __restrict__ X,
                                            const float* __restrict__ om,
                                            const float* __restrict__ ph,
                                            float* __restrict__ XS) {
    int i = blockIdx.x * 256 + threadIdx.x;
    if (i >= B_*L_*3*D_) return;
    int d  = i % D_;
    int ch = (i / D_) % 3;
    int bt = i / (3*D_);
    XS[i] = cosf(X[bt*3 + ch] * om[ch*D_ + d] + ph[ch*D_ + d]);
}

// ---------------- build x0 for a chunk of 5 lidx ----------------
__global__ __launch_bounds__(256) void k_x0(const float* __restrict__ XS,
                                            const float* __restrict__ targets,
                                            const int* __restrict__ perms,
                                            float* __restrict__ x, int cb) {
    int i = blockIdx.x * 256 + threadIdx.x;
    if (i >= MTOK*E_) return;
    int e   = i % E_;
    int tok = i / E_;
    int s   = tok % SEQ_;
    int bi  = (tok / SEQ_) % B_;
    int c   = tok / (SEQ_*B_);
    int cl  = cb + c;
    int lidx = cl + 1;
    int pb  = perms[cl*B_ + bi];
    float val;
    if (s < 3) {
        int t = (e < D_) ? (L_ - lidx) : (L_ - lidx - 1);
        int d = (e < D_) ? e : (e - D_);
        val = XS[((pb*L_ + t)*3 + s)*D_ + d];
    } else if (s < 6) {
        int t = (17 - lidx) & 15;
        val = targets[(pb*L_ + t)*3 + (s - 3)];
    } else {
        val = (float)(L_ - lidx);
    }
    x[i] = val;
}

// ---------------- LayerNorm: one wave per token, no barriers ----------------
__global__ __launch_bounds__(256) void k_ln(const float* __restrict__ x,
                                            const float* __restrict__ g,
                                            const float* __restrict__ b,
                                            __hip_bfloat16* __restrict__ h) {
    int gi = blockIdx.x * 256 + threadIdx.x;
    int tok = gi >> 6, lane = gi & 63;
    const float4* xr = (const float4*)(x + (size_t)tok * E_);
    float4 v0 = xr[lane], v1 = xr[lane + 64], v2 = xr[lane + 128];
    float s = v0.x+v0.y+v0.z+v0.w + v1.x+v1.y+v1.z+v1.w + v2.x+v2.y+v2.z+v2.w;
    #pragma unroll
    for (int o = 32; o > 0; o >>= 1) s += __shfl_xor(s, o, 64);
    float mu = s * (1.0f / E_);
    v0.x-=mu; v0.y-=mu; v0.z-=mu; v0.w-=mu;
    v1.x-=mu; v1.y-=mu; v1.z-=mu; v1.w-=mu;
    v2.x-=mu; v2.y-=mu; v2.z-=mu; v2.w-=mu;
    float q = v0.x*v0.x+v0.y*v0.y+v0.z*v0.z+v0.w*v0.w
            + v1.x*v1.x+v1.y*v1.y+v1.z*v1.z+v1.w*v1.w
            + v2.x*v2.x+v2.y*v2.y+v2.z*v2.z+v2.w*v2.w;
    #pragma unroll
    for (int o = 32; o > 0; o >>= 1) q += __shfl_xor(q, o, 64);
    float rstd = rsqrtf(q * (1.0f / E_) + LN_EPS);
    const float4* g4 = (const float4*)g;
    const float4* b4 = (const float4*)b;
    ushort4* h4 = (ushort4*)(h + (size_t)tok * E_);
    #pragma unroll
    for (int k = 0; k < 3; k++) {
        float4 v = (k == 0) ? v0 : (k == 1) ? v1 : v2;
        float4 gg = g4[lane + k*64], bb = b4[lane + k*64];
        ushort4 o;
        o.x = __bfloat16_as_ushort(__float2bfloat16(v.x * rstd * gg.x + bb.x));
        o.y = __bfloat16_as_ushort(__float2bfloat16(v.y * rstd * gg.y + bb.y));
        o.z = __bfloat16_as_ushort(__float2bfloat16(v.z * rstd * gg.z + bb.z));
        o.w = __bfloat16_as_ushort(__float2bfloat16(v.w * rstd * gg.w + bb.w));
        h4[lane + k*64] = o;
    }
}

// ---------------- per-layer weight transpose+convert fp32[K][N] -> bf16[N][K] ----------------
__global__ __launch_bounds__(256) void k_cvt(const float* __restrict__ Wq,
                                             const float* __restrict__ Wk,
                                             const float* __restrict__ Wv,
                                             const float* __restrict__ Wo,
                                             const float* __restrict__ W1,
                                             const float* __restrict__ W2,
                                             const float* __restrict__ bq,
                                             const float* __restrict__ bk,
                                             const float* __restrict__ bv,
                                             __hip_bfloat16* __restrict__ wl,
                                             float* __restrict__ bqkv, int l) {
    int bid = blockIdx.x;
    int tid = threadIdx.x;
    if (bid == 6912) {
        for (int i = tid; i < 2304; i += 256) {
            float v = (i < 768) ? bq[l*768 + i] : (i < 1536) ? bk[l*768 + i - 768]
                                                             : bv[l*768 + i - 1536];
            bqkv[i] = v;
        }
        return;
    }
    const float* src; __hip_bfloat16* dst; int K, N, ti, tj;
    if (bid < 1728) {
        int part = bid / 576, idx = bid % 576;
        const float* srcs[3] = {Wq, Wk, Wv};
        src = srcs[part] + (size_t)l*768*768; dst = wl + (size_t)part*768*768;
        K = 768; N = 768; tj = idx % 24; ti = idx / 24;
    } else if (bid < 2304) {
        int idx = bid - 1728;
        src = Wo + (size_t)l*768*768; dst = wl + 1769472;
        K = 768; N = 768; tj = idx % 24; ti = idx / 24;
    } else if (bid < 4608) {
        int idx = bid - 2304;
        src = W1 + (size_t)l*768*3072; dst = wl + 2359296;
        K = 768; N = 3072; tj = idx % 96; ti = idx / 96;
    } else {
        int idx = bid - 4608;
        src = W2 + (size_t)l*3072*768; dst = wl + 4718592;
        K = 3072; N = 768; tj = idx % 24; ti = idx / 24;
    }
    __shared__ float tbuf[32][33];
    int tx = tid & 31, ty = tid >> 5;
    #pragma unroll
    for (int p = 0; p < 4; p++) {
        int k = ti*32 + ty + p*8, n = tj*32 + tx;
        tbuf[ty + p*8][tx] = src[(size_t)k*N + n];
    }
    __syncthreads();
    #pragma unroll
    for (int p = 0; p < 4; p++) {
        int n = tj*32 + ty + p*8, k = ti*32 + tx;
        dst[(size_t)n*K + k] = __float2bfloat16(tbuf[tx][ty + p*8]);
    }
}

// ---------------- bf16 MFMA GEMM: C(+)= A[M][K] @ Bt[N][K]^T, tile 128xBN_ ----------------
// flags: 1 = bf16 out, 2 = fp32 accumulate (+=), 4 = relu
template<int BN_>
__global__ __launch_bounds__(256) void k_gemm_t(const __hip_bfloat16* __restrict__ A,
                                                const __hip_bfloat16* __restrict__ Bt,
                                                const float* __restrict__ bias,
                                                void* __restrict__ Cp,
                                                int K, int ldc, int flags) {
    constexpr int NF = BN_ / 32;                  // B frags per wave (4 or 2)
    __shared__ __align__(16) char smem[8192 + BN_*64];
    char* As = smem;
    char* Bs = smem + 8192;
    int tid = threadIdx.x;
    int lane = tid & 63;
    int w = tid >> 6;
    int wm = (w >> 1) * 64, wn = (w & 1) * (BN_/2);
    int m0 = blockIdx.y * 128, n0 = blockIdx.x * BN_;

    int u1 = tid, u2 = tid + 256;
    int r1 = u1 >> 2, kg1 = ((u1 & 3) ^ ((r1 >> 1) & 3)) * 8;
    int r2 = u2 >> 2, kg2 = ((u2 & 3) ^ ((r2 >> 1) & 3)) * 8;

    f32x4 acc[4][NF] = {};
    int fr = lane & 15, fkg = lane >> 4;

    for (int k0 = 0; k0 < K; k0 += 32) {
        GLOAD_LDS16(A  + (size_t)(m0 + r1) * K + k0 + kg1, As + u1 * 16);
        GLOAD_LDS16(A  + (size_t)(m0 + r2) * K + k0 + kg2, As + u2 * 16);
        GLOAD_LDS16(Bt + (size_t)(n0 + r1) * K + k0 + kg1, Bs + u1 * 16);
        if (BN_ == 128)
            GLOAD_LDS16(Bt + (size_t)(n0 + r2) * K + k0 + kg2, Bs + u2 * 16);
        __syncthreads();
        bf16x8 a[4], b[NF];
        #pragma unroll
        for (int i = 0; i < 4; i++) {
            int m = wm + i*16 + fr;
            a[i] = *(const bf16x8*)(As + m*64 + ((fkg ^ ((m >> 1) & 3)) * 16));
        }
        #pragma unroll
        for (int j = 0; j < NF; j++) {
            int n = wn + j*16 + fr;
            b[j] = *(const bf16x8*)(Bs + n*64 + ((fkg ^ ((n >> 1) & 3)) * 16));
        }
        #pragma unroll
        for (int i = 0; i < 4; i++)
            #pragma unroll
            for (int j = 0; j < NF; j++)
                acc[i][j] = __builtin_amdgcn_mfma_f32_16x16x32_bf16(a[i], b[j], acc[i][j], 0, 0, 0);
        __syncthreads();
    }

    int colL = lane & 15, rowg = (lane >> 4) * 4;
    #pragma unroll
    for (int i = 0; i < 4; i++) {
        #pragma unroll
        for (int j = 0; j < NF; j++) {
            int col = n0 + wn + j*16 + colL;
            float bv = bias ? bias[col] : 0.0f;
            #pragma unroll
            for (int r = 0; r < 4; r++) {
                int row = m0 + wm + i*16 + rowg + r;
                float v = acc[i][j][r] + bv;
                if (flags & 4) v = fmaxf(v, 0.0f);
                size_t off = (size_t)row * ldc + col;
                if (flags & 1)      ((__hip_bfloat16*)Cp)[off] = __float2bfloat16(v);
                else if (flags & 2) ((float*)Cp)[off] += v;
                else                ((float*)Cp)[off] = v;
            }
        }
    }
}

// ---------------- attention ----------------
__global__ __launch_bounds__(256) void k_attn(const __hip_bfloat16* __restrict__ qkv,
                                              __hip_bfloat16* __restrict__ o) {
    __shared__ float qs[SEQ_][HD_], ks[SEQ_][HD_], vs[SEQ_][HD_];
    __shared__ float att[SEQ_][SEQ_];
    int blk = blockIdx.x;
    int hh  = blk % H_;
    int cbb = blk / H_;
    int t = threadIdx.x;
    for (int i = t; i < SEQ_*HD_; i += 256) {
        int s = i / HD_, d = i % HD_;
        size_t g = (size_t)(cbb*SEQ_ + s) * 2304 + hh*64 + d;
        qs[s][d] = __bfloat162float(qkv[g]);
        ks[s][d] = __bfloat162float(qkv[g + 768]);
        vs[s][d] = __bfloat162float(qkv[g + 1536]);
    }
    __syncthreads();
    if (t < SEQ_*SEQ_) {
        int qi = t / SEQ_, kj = t % SEQ_;
        float s = 0.f;
        #pragma unroll
        for (int d = 0; d < HD_; d++) s += qs[qi][d] * ks[kj][d];
        att[qi][kj] = s * 0.125f;
    }
    __syncthreads();
    if (t < SEQ_) {
        float mx = -1e30f;
        #pragma unroll
        for (int j = 0; j < SEQ_; j++) mx = fmaxf(mx, att[t][j]);
        float e[SEQ_]; float sum = 0.f;
        #pragma unroll
        for (int j = 0; j < SEQ_; j++) { e[j] = expf(att[t][j] - mx); sum += e[j]; }
        float inv = 1.f / sum;
        #pragma unroll
        for (int j = 0; j < SEQ_; j++) att[t][j] = e[j] * inv;
    }
    __syncthreads();
    for (int i = t; i < SEQ_*HD_; i += 256) {
        int s = i / HD_, d = i % HD_;
        float acc = 0.f;
        #pragma unroll
        for (int j = 0; j < SEQ_; j++) acc += att[s][j] * vs[j][d];
        o[(size_t)(cbb*SEQ_ + s) * 768 + hh*64 + d] = __float2bfloat16(acc);
    }
}

// ---------------- logits ----------------
__global__ __launch_bounds__(256) void k_logits(const __hip_bfloat16* __restrict__ hfin,
                                                const float* __restrict__ Wout,
                                                const float* __restrict__ bout,
                                                float* __restrict__ logits, int cb) {
    __shared__ float red[3][256];
    int blk = blockIdx.x;
    int t = threadIdx.x;
    const __hip_bfloat16* row = hfin + (size_t)blk * SEQ_ * E_;
    float a0 = 0.f, a1 = 0.f, a2 = 0.f;
    for (int e = t; e < SEQ_*E_; e += 256) {
        float x = __bfloat162float(row[e]);
        a0 += x * Wout[e*3 + 0]; a1 += x * Wout[e*3 + 1]; a2 += x * Wout[e*3 + 2];
    }
    red[0][t] = a0; red[1][t] = a1; red[2][t] = a2;
    __syncthreads();
    for (int o = 128; o > 0; o >>= 1) {
        if (t < o) { red[0][t] += red[0][t+o]; red[1][t] += red[1][t+o]; red[2][t] += red[2][t+o]; }
        __syncthreads();
    }
    if (t < 3) logits[((size_t)cb*B_ + blk)*3 + t] = red[t][0] + bout[t];
}

// ---------------- cost matrix ----------------
__global__ __launch_bounds__(256) void k_cost(const float* __restrict__ logits,
                                              const float* __restrict__ targets,
                                              float* __restrict__ cost) {
    int i = blockIdx.x * 256 + threadIdx.x;
    if (i >= 15*B_*B_) return;
    int j  = i & 127;
    int r  = (i >> 7) & 127;
    int cl = i >> 14;
    int lidx = cl + 1;
    const float* lg = &logits[(cl*B_ + r) * 3];
    const float* tg = &targets[((size_t)j*L_ + (L_ - lidx)) * 3];
    float d0 = lg[0]-tg[0], d1 = lg[1]-tg[1], d2 = lg[2]-tg[2];
    cost[i] = sqrtf(d0*d0 + d1*d1 + d2*d2 + 1e-12f);
}

// ---------------- greedy matching: 1024 threads, 16 keys/thread (no spill) ----------------
__global__ __launch_bounds__(1024) void k_match(const float* __restrict__ cost,
                                                const float* __restrict__ logits,
                                                const float* __restrict__ targets,
                                                float* __restrict__ losses) {
    __shared__ unsigned long long wred[16];
    __shared__ int mrow[B_];
    __shared__ unsigned int winner;
    __shared__ float lred[B_];
    int cl = blockIdx.x, t = threadIdx.x;
    const float* cst = cost + (size_t)cl * B_ * B_;
    unsigned long long key[16];
    #pragma unroll
    for (int n = 0; n < 16; n++) {
        unsigned e = n * 1024 + t;
        key[n] = ((unsigned long long)__float_as_uint(cst[e]) << 32) | e;
    }
    int lane = t & 63, w = t >> 6;
    for (int it = 0; it < B_; it++) {
        unsigned long long best = ~0ull;
        #pragma unroll
        for (int n = 0; n < 16; n++) best = key[n] < best ? key[n] : best;
        #pragma unroll
        for (int o = 32; o > 0; o >>= 1) {
            unsigned long long other = __shfl_down(best, o, 64);
            best = other < best ? other : best;
        }
        if (lane == 0) wred[w] = best;
        __syncthreads();
        if (t == 0) {
            unsigned long long b = wred[0];
            #pragma unroll
            for (int q = 1; q < 16; q++) if (wred[q] < b) b = wred[q];
            unsigned e = (unsigned)b;
            winner = e;
            mrow[(e >> 7) & 127] = e & 127;
        }
        __syncthreads();
        unsigned e = winner;
        unsigned wi = (e >> 7) & 127, wj = e & 127;
        #pragma unroll
        for (int n = 0; n < 16; n++) {
            unsigned ke = (unsigned)key[n];
            bool dead = (((ke >> 7) & 127) == wi) | ((ke & 127) == wj);
            key[n] = dead ? ~0ull : key[n];
        }
        __syncthreads();
    }
    int lidx = cl + 1;
    if (t < B_) {
        const float* lg = &logits[(cl*B_ + mrow[t]) * 3];
        const float* tg = &targets[((size_t)t*L_ + (L_ - lidx)) * 3];
        float d0 = lg[0]-tg[0], d1 = lg[1]-tg[1], d2 = lg[2]-tg[2];
        lred[t] = d0*d0 + d1*d1 + d2*d2;
    }
    __syncthreads();
    for (int o = 64; o > 0; o >>= 1) {
        if (t < o) lred[t] += lred[t+o];
        __syncthreads();
    }
    if (t == 0) losses[cl] = lred[0] * (1.0f / (B_*3));
}

__global__ void k_final(const float* __restrict__ losses, float* __restrict__ out) {
    float s = 0.f;
    for (int i = 0; i < 15; i++) s += losses[i];
    out[0] = s * (1.0f / 15.0f);
}

extern "C" void kernel_launch(void* const* d_in, const int* in_sizes, int n_in,
                              void* d_out, int out_size, void* d_ws, size_t ws_size,
                              hipStream_t stream) {
    (void)in_sizes; (void)n_in; (void)out_size;
    const float* X       = (const float*)d_in[0];
    const float* targets = (const float*)d_in[1];
    const float* omegas  = (const float*)d_in[2];
    const float* phases  = (const float*)d_in[3];
    const int*   perms   = (const int*)d_in[4];
    const float* Wq  = (const float*)d_in[5];
    const float* bq  = (const float*)d_in[6];
    const float* Wk  = (const float*)d_in[7];
    const float* bk  = (const float*)d_in[8];
    const float* Wv  = (const float*)d_in[9];
    const float* bv  = (const float*)d_in[10];
    const float* Wo  = (const float*)d_in[11];
    const float* bo  = (const float*)d_in[12];
    const float* ln1g = (const float*)d_in[13];
    const float* ln1b = (const float*)d_in[14];
    const float* ln2g = (const float*)d_in[15];
    const float* ln2b = (const float*)d_in[16];
    const float* W1  = (const float*)d_in[17];
    const float* b1f = (const float*)d_in[18];
    const float* W2  = (const float*)d_in[19];
    const float* b2f = (const float*)d_in[20];
    const float* lnfg = (const float*)d_in[21];
    const float* lnfb = (const float*)d_in[22];
    const float* Wout = (const float*)d_in[23];
    const float* bout = (const float*)d_in[24];

    // ws_size is constant across calls -> this branch is call-invariant (graph-safe).
    bool big = ws_size >= 179000000ull;   // hoisted 6-layer weight pack fits

    char* wsb = (char*)d_ws;
    size_t off = 0;
    auto alloc = [&](size_t bytes) {
        char* p = wsb + off;
        off += (bytes + 255) & ~(size_t)255;
        return p;
    };
    float*          XS     = (float*)alloc(9437184);
    float*          x      = (float*)alloc(23592960);
    __hip_bfloat16* h      = (__hip_bfloat16*)alloc(11796480);
    __hip_bfloat16* qkvh   = (__hip_bfloat16*)alloc(47185920);
    __hip_bfloat16* wl     = (__hip_bfloat16*)alloc(big ? (size_t)6*WLS*2 : (size_t)WLS*2);
    float*          bqkv   = (float*)alloc(big ? 6*BQS*4 : BQS*4);
    float*          logits = (float*)alloc(23040);
    float*          costb  = (float*)alloc(983040);
    float*          losses = (float*)alloc(64);

    k_xs<<<(B_*L_*3*D_ + 255)/256, 256, 0, stream>>>(X, omegas, phases, XS);

    if (big) {
        for (int l = 0; l < NL_; l++)
            k_cvt<<<6913, 256, 0, stream>>>(Wq, Wk, Wv, Wo, W1, W2, bq, bk, bv,
                                            wl + (size_t)l*WLS, bqkv + l*BQS, l);
    }

    dim3 gQKV(2304/128, MTOK/128);   // 18 x 60
    dim3 gF1 (3072/128, MTOK/128);   // 24 x 60
    dim3 gO64(768/64,   MTOK/128);   // 12 x 60
    dim3 gLN (MTOK/4);               // wave per token

    for (int cb = 0; cb < 15; cb += CH_) {
        k_x0<<<(MTOK*E_ + 255)/256, 256, 0, stream>>>(XS, targets, perms, x, cb);
        for (int l = 0; l < NL_; l++) {
            __hip_bfloat16* wlp = big ? wl + (size_t)l*WLS : wl;
            float*          bqp = big ? bqkv + l*BQS : bqkv;
            if (!big)
                k_cvt<<<6913, 256, 0, stream>>>(Wq, Wk, Wv, Wo, W1, W2, bq, bk, bv, wlp, bqp, l);
            k_ln<<<gLN, 256, 0, stream>>>(x, ln1g + l*E_, ln1b + l*E_, h);
            k_gemm_t<128><<<gQKV, 256, 0, stream>>>(h, wlp, bqp, qkvh, 768, 2304, 1);
            k_attn<<<CH_*B_*H_, 256, 0, stream>>>(qkvh, h);
            k_gemm_t<64><<<gO64, 256, 0, stream>>>(h, wlp + 1769472, bo + l*E_, x, 768, 768, 2);
            k_ln<<<gLN, 256, 0, stream>>>(x, ln2g + l*E_, ln2b + l*E_, h);
            k_gemm_t<128><<<gF1, 256, 0, stream>>>(h, wlp + 2359296, b1f + l*3072, qkvh, 768, 3072, 1|4);
            k_gemm_t<64><<<gO64, 256, 0, stream>>>(qkvh, wlp + 4718592, b2f + l*E_, x, 3072, 768, 2);
        }
        k_ln<<<gLN, 256, 0, stream>>>(x, lnfg, lnfb, h);
        k_logits<<<CH_*B_, 256, 0, stream>>>(h, Wout, bout, logits, cb);
    }
    k_cost<<<(15*B_*B_ + 255)/256, 256, 0, stream>>>(logits, targets, costb);
    k_match<<<15, 1024, 0, stream>>>(costb, logits, targets, losses);
    k_final<<<1, 1, 0, stream>>>(losses, (float*)d_out);
}